// Round 7
// baseline (271.975 us; speedup 1.0000x reference)
//
#include <hip/hip_runtime.h>
#include <cstdint>

typedef unsigned short ushort_t;
typedef __bf16 bf16x8 __attribute__((ext_vector_type(8)));
typedef ushort_t u16x8 __attribute__((ext_vector_type(8)));
typedef float f32x4 __attribute__((ext_vector_type(4)));
typedef uint32_t u32x4 __attribute__((ext_vector_type(4)));

#define RMS_EPS 1.1920928955078125e-07f
// B=8 T=4096 C=256 Wh=1024 E=8 K=2 ; tokens NT=32768, pairs NP=65536

__device__ __forceinline__ ushort_t f2bf(float f) {
  uint32_t u = __builtin_bit_cast(uint32_t, f);
  u += 0x7fffu + ((u >> 16) & 1u);   // RNE
  return (ushort_t)(u >> 16);
}

__device__ __forceinline__ void g2l16(const ushort_t* g, ushort_t* l) {
  __builtin_amdgcn_global_load_lds(
      (const __attribute__((address_space(1))) uint32_t*)g,
      (__attribute__((address_space(3))) uint32_t*)l, 16, 0, 0);
}

__device__ __forceinline__ f32x4 mfma32(bf16x8 a, bf16x8 b, f32x4 c) {
  return __builtin_amdgcn_mfma_f32_16x16x32_bf16(a, b, c, 0, 0, 0);
}

// GELU via odd-poly erf approx (validated r3-r6, absmax 8.0 vs thr 41.6)
__device__ __forceinline__ float gelu1(float v) {
  float vc = fminf(fmaxf(v, -2.9f), 2.9f);   // v_med3
  float x2 = vc * vc;
  float p = fmaf(-0.000414256f, x2, 0.0107517f);
  p = fmaf(p, x2, -0.1136149f);
  p = fmaf(p, x2, 0.786301f);
  float E = vc * p;
  float t = 0.5f * v;
  return fmaf(t, E, t);
}

// ---- fused pre-pass: pack_w (blocks 0..511) | route (512..767) ----
// rmsnorm folded into moe_mlp's prologue (r5-verified math).
__global__ __launch_bounds__(256) void fused_pre(
    const float* __restrict__ W1, const float* __restrict__ W2,
    ushort_t* __restrict__ w1f, ushort_t* __restrict__ w2f,
    const int* __restrict__ eids, int* __restrict__ cnt,
    int* __restrict__ lists) {
  __shared__ ushort_t tile[64][130];
  __shared__ int lcnt[8], lbase[8];
  int bid = blockIdx.x;
  int t = threadIdx.x;

  if (bid < 512) {
    // ---- pack W1/W2 into MFMA fragment order via LDS tile ----
    // W1 (K=32 frags): unit = e*32768 + ch*1024 + kk*128 + nt*64 + lane;
    //   elem j = W1[e][kk*32+quad*8+j][ch*32+nt*16+l16]
    // W2 (half-interleaved, A-operand of concat-K32 GEMM2):
    //   unit U = ((e*32+ch)*16+ct)*64 + lane ;
    //   elem j   = W2[e][ch*32 +  0 + quad*4+j][ct*16+l16]
    //   elem 4+j = W2[e][ch*32 + 16 + quad*4+j][ct*16+l16]
    int b = bid;
    int isW2 = b >= 256;
    const float* src; ushort_t* dst; int e, kt, wt, rs;
    if (!isW2) { e = b >> 5; kt = (b >> 3) & 3; wt = b & 7; src = W1; dst = w1f; rs = 1024; }
    else { b -= 256; e = b >> 5; kt = (b >> 1) & 15; wt = b & 1; src = W2; dst = w2f; rs = 256; }
    int k0 = kt * 64, c0 = wt * 128;
    const float* sb = src + ((size_t)e << 18) + (size_t)k0 * rs + c0;
#pragma unroll
    for (int i = 0; i < 8; ++i) {
      int f = i * 1024 + t * 4;          // [0,8192)
      int r = f >> 7, c = f & 127;
      float4 v = *reinterpret_cast<const float4*>(sb + (size_t)r * rs + c);
      ushort2 lo, hi;
      lo.x = f2bf(v.x); lo.y = f2bf(v.y); hi.x = f2bf(v.z); hi.y = f2bf(v.w);
      *reinterpret_cast<ushort2*>(&tile[r][c]) = lo;
      *reinterpret_cast<ushort2*>(&tile[r][c + 2]) = hi;
    }
    __syncthreads();
    int lane = t & 63, l16 = lane & 15, quad = lane >> 4;
    int wave = t >> 6;
    if (!isW2) {
#pragma unroll
      for (int p = 0; p < 4; ++p) {
        int u = p * 256 + t;               // [0,1024)
        int kk2 = (u >> 9) & 1;
        int rr = kk2 * 32 + quad * 8;
        int nt = (u >> 6) & 1, chL = (u >> 7) & 3;
        int cc = chL * 32 + nt * 16 + l16;
        u16x8 o;
#pragma unroll
        for (int j = 0; j < 8; ++j) o[j] = tile[rr + j][cc];
        size_t U = ((size_t)e * 32768) + (size_t)(wt * 4 + chL) * 1024 + (kt * 2 + kk2) * 128 + nt * 64 + lane;
        *reinterpret_cast<u16x8*>(dst + U * 8) = o;
      }
    } else {
#pragma unroll
      for (int p = 0; p < 4; ++p) {
        int u = p * 4 + wave;              // [0,16): chL(2) x ctL(8)
        int chL = u >> 3, ctL = u & 7;
        int cc = ctL * 16 + l16;
        u16x8 o;
#pragma unroll
        for (int j = 0; j < 4; ++j) o[j] = tile[chL * 32 + quad * 4 + j][cc];
#pragma unroll
        for (int j = 0; j < 4; ++j) o[4 + j] = tile[chL * 32 + 16 + quad * 4 + j][cc];
        size_t U = (((size_t)(e * 32 + kt * 2 + chL) * 16) + (wt * 8 + ctL)) * 64 + lane;
        *reinterpret_cast<u16x8*>(dst + U * 8) = o;
      }
    }
  } else {
    // ---- route (t,k) pairs into per-expert lists ----
    if (t < 8) lcnt[t] = 0;
    __syncthreads();
    int p = (bid - 512) * 256 + t;
    int e = eids[p];
    int lpos = atomicAdd(&lcnt[e], 1);
    __syncthreads();
    if (t < 8) lbase[t] = atomicAdd(&cnt[t], lcnt[t]);
    __syncthreads();
    lists[e * 65536 + lbase[e] + lpos] = p;
  }
}

// ---- fused expert MLP (RMSNorm prologue + global-W2 GEMM2) ----
// r6 post-mortem: LDS read pipe ~68% busy (128 ds_read_b128/chunk-block,
// 4x wave-redundant) was the binder; vmcnt/setprio games were null.
// This build removes GEMM2's LDS reads entirely: W2 fragments are read
// per-wave DIRECT from global (lane-major packed layout -> 1KB coalesced
// dwordx4 per fragment; 4 barrier-locked waves + co-resident blocks hit
// the same 16KB chunk window -> L1/L2 serve the redundancy, not LDS).
// W1 keeps the proven LDS double-buffer. One barrier/chunk. LDS 32KB.
// RMSNorm folded into the A-fragment prologue (one pass, r5-verified).
// Regs ~150 -> launch_bounds(256,3) for 3 waves/SIMD.
__global__ __launch_bounds__(256, 3) void moe_mlp(
    const float* __restrict__ x,       // [32768][256] f32
    const float* __restrict__ rw,      // [256]
    const ushort_t* __restrict__ w1f,  // [8][32][8][2][64][8]
    const ushort_t* __restrict__ w2f,  // [8][32][16][64][8]
    const float* __restrict__ b1,      // [8][1024]
    const float* __restrict__ b2,      // [8][256]
    const int* __restrict__ cnt,       // [8]
    const int* __restrict__ lists,     // [8][65536]
    float* __restrict__ out)           // [65536][256]
{
  __shared__ __align__(16) ushort_t w1b[2][8192];   // 2 x 16KB (W1 only)

  // bijective XCD swizzle; gridDim.x = 1032 = 8*129 exactly
  int cpx = gridDim.x >> 3;
  int flat = (blockIdx.x & 7) * cpx + (blockIdx.x >> 3);

  int e = -1, tile = 0, accum = 0, n_e = 0;
#pragma unroll
  for (int i = 0; i < 8; ++i) {
    int c = cnt[i];
    int ti = (c + 63) >> 6;
    if (e < 0 && flat < accum + ti) { e = i; tile = flat - accum; n_e = c; }
    accum += ti;
  }
  if (e < 0) return;
  int start = tile * 64;

  int tid = threadIdx.x;
  int wave = tid >> 6, lane = tid & 63, l16 = lane & 15, quad = lane >> 4;

  const ushort_t* w1e = w1f + ((size_t)e << 18);
  const ushort_t* w2e = w2f + ((size_t)e << 18);
  const int* le = lists + e * 65536;

  // this wave's 16 token rows, register-resident
  int gi = start + wave * 16 + l16;
  int pr = le[(gi < n_e) ? gi : 0];

  // stage W1(0) into buffer 0 FIRST (latency hides under RMS prologue)
#pragma unroll
  for (int j = 0; j < 4; ++j) {
    int p = j * 4 + wave;
    g2l16(w1e + p * 512 + lane * 8, &w1b[0][p * 512]);
  }

  // ---- A fragments with in-prologue RMSNorm (one pass, values in regs) ----
  // Token row (256 f32) spread over the 4 quad-lanes of this l16 group
  // (64 f32 each: k = kk*32 + quad*8 + j). Reduce via shfl_xor(16,32).
  bf16x8 afr[8];
  {
    const float* xr = x + (size_t)(pr >> 1) * 256 + quad * 8;
    float4 ra[8], rb[8];
    float s = 0.f;
#pragma unroll
    for (int kk = 0; kk < 8; ++kk) {
      ra[kk] = *reinterpret_cast<const float4*>(xr + kk * 32);
      rb[kk] = *reinterpret_cast<const float4*>(xr + kk * 32 + 4);
      s += ra[kk].x * ra[kk].x + ra[kk].y * ra[kk].y + ra[kk].z * ra[kk].z + ra[kk].w * ra[kk].w;
      s += rb[kk].x * rb[kk].x + rb[kk].y * rb[kk].y + rb[kk].z * rb[kk].z + rb[kk].w * rb[kk].w;
    }
    s += __shfl_xor(s, 16);
    s += __shfl_xor(s, 32);
    float inv = rsqrtf(s * (1.0f / 256.0f) + RMS_EPS);
#pragma unroll
    for (int kk = 0; kk < 8; ++kk) {
      float4 wa = *reinterpret_cast<const float4*>(rw + kk * 32 + quad * 8);
      float4 wb = *reinterpret_cast<const float4*>(rw + kk * 32 + quad * 8 + 4);
      u16x8 t0;
      t0[0] = f2bf(ra[kk].x * inv * wa.x); t0[1] = f2bf(ra[kk].y * inv * wa.y);
      t0[2] = f2bf(ra[kk].z * inv * wa.z); t0[3] = f2bf(ra[kk].w * inv * wa.w);
      t0[4] = f2bf(rb[kk].x * inv * wb.x); t0[5] = f2bf(rb[kk].y * inv * wb.y);
      t0[6] = f2bf(rb[kk].z * inv * wb.z); t0[7] = f2bf(rb[kk].w * inv * wb.w);
      afr[kk] = __builtin_bit_cast(bf16x8, t0);
    }
  }

  f32x4 acc[16];
#pragma unroll
  for (int ct = 0; ct < 16; ++ct) acc[ct] = (f32x4){0.f, 0.f, 0.f, 0.f};

  const float* b1e = b1 + e * 1024;

  for (int ch = 0; ch < 32; ++ch) {
    int cur = ch & 1;
    // __syncthreads emits vmcnt(0)+barrier: each wave's own g2l16 for
    // w1b[cur] (issued last iter) retired pre-barrier -> staged for ALL.
    __syncthreads();

    // prefetch W1(ch+1) -> alternate buffer (lands by next barrier)
    if (ch + 1 < 32) {
      const ushort_t* n1 = w1e + (ch + 1) * 8192;
#pragma unroll
      for (int j = 0; j < 4; ++j) {
        int p = j * 4 + wave;
        g2l16(n1 + p * 512 + lane * 8, &w1b[cur ^ 1][p * 512]);
      }
    }

    // GEMM1 (swapped): hT ; 2 independent chains x 8 deep (LDS reads)
    const ushort_t* l1 = w1b[cur];
    f32x4 ht0 = (f32x4){0.f, 0.f, 0.f, 0.f};
    f32x4 ht1 = (f32x4){0.f, 0.f, 0.f, 0.f};
#pragma unroll
    for (int kk = 0; kk < 8; ++kk) {
      bf16x8 wA = *reinterpret_cast<const bf16x8*>(l1 + ((kk * 2 + 0) * 64 + lane) * 8);
      bf16x8 wB = *reinterpret_cast<const bf16x8*>(l1 + ((kk * 2 + 1) * 64 + lane) * 8);
      ht0 = mfma32(wA, afr[kk], ht0);
      ht1 = mfma32(wB, afr[kk], ht1);
    }

    int w0 = ch * 32;
    f32x4 bia0 = *reinterpret_cast<const f32x4*>(b1e + w0 + quad * 4);
    f32x4 bia1 = *reinterpret_cast<const f32x4*>(b1e + w0 + 16 + quad * 4);

    // GELU + bf16 pack in registers. elems 0-3 = nt0 half, 4-7 = nt1 half
    // — matches W2 frag interleave (r2-verified).
    u16x8 hp;
#pragma unroll
    for (int rr = 0; rr < 4; ++rr) {
      hp[rr]     = f2bf(gelu1(ht0[rr] + bia0[rr]));
      hp[4 + rr] = f2bf(gelu1(ht1[rr] + bia1[rr]));
    }
    bf16x8 hF = __builtin_bit_cast(bf16x8, hp);

    // GEMM2: yT[16 tok x 256] += W2^T . hT via K=32 MFMA.
    // W2 fragments DIRECT FROM GLOBAL (coalesced 1KB/frag; L1-served
    // across the 4 lockstep waves) — zero LDS traffic on this phase.
    const ushort_t* w2g = w2e + ch * 8192;
#pragma unroll
    for (int ct = 0; ct < 16; ++ct) {
      bf16x8 wq = *reinterpret_cast<const bf16x8*>(w2g + (ct * 64 + lane) * 8);
      acc[ct] = mfma32(wq, hF, acc[ct]);
    }
  }

  // epilogue: +b2, masked float4 store (4 consecutive cols per lane)
  const float* b2e = b2 + e * 256;
  if (gi < n_e) {
    float* orow = out + (size_t)pr * 256;
#pragma unroll
    for (int ct = 0; ct < 16; ++ct) {
      f32x4 bv = *reinterpret_cast<const f32x4*>(b2e + ct * 16 + quad * 4);
      f32x4 o = acc[ct] + bv;
      *reinterpret_cast<f32x4*>(orow + ct * 16 + quad * 4) = o;
    }
  }
}

extern "C" void kernel_launch(void* const* d_in, const int* in_sizes, int n_in,
                              void* d_out, int out_size, void* d_ws, size_t ws_size,
                              hipStream_t stream) {
  const float* x  = (const float*)d_in[0];
  const float* rw = (const float*)d_in[1];
  const float* W1 = (const float*)d_in[2];
  const float* b1 = (const float*)d_in[3];
  const float* W2 = (const float*)d_in[4];
  const float* b2 = (const float*)d_in[5];
  const int* eids = (const int*)d_in[6];
  float* out = (float*)d_out;

  char* ws = (char*)d_ws;
  ushort_t* w1f = (ushort_t*)(ws);              //  4,194,304 B
  ushort_t* w2f = (ushort_t*)(ws + 4194304);    //  4,194,304 B
  int* cnt      = (int*)(ws + 8388608);         //  256 B (8 used)
  int* lists    = (int*)(ws + 8388864);         //  2,097,152 B

  hipMemsetAsync(cnt, 0, 8 * sizeof(int), stream);
  // pre-pass: pack_w (512 blocks) + route (256 blocks)
  fused_pre<<<768, 256, 0, stream>>>(W1, W2, w1f, w2f, eids, cnt, lists);
  // max tiles = sum_e ceil(c_e/64) <= 65536/64 + 8 = 1032 (= 8*129)
  moe_mlp<<<1032, 256, 0, stream>>>(x, rw, w1f, w2f, b1, b2, cnt, lists, out);
}